// Round 1
// baseline (556.420 us; speedup 1.0000x reference)
//
#include <hip/hip_runtime.h>

// BranchNet: out[n] = x[n] @ W_fold[argmin_b(x[n]@W_comb[:,b]+b_comb[b])] + b_fold[sel]
// W_comb = W_base@W_est.T (fp64), W_fold[b] = W_base@W_clf[b] (bf16, [b][c][k]).
// Sizes: N=131072, IN=256, HID=256, B=8, C=128.

#define NROWS  131072
#define RROWS  128          // rows per block in main kernel
#define SMEM_MAIN 70308     // see layout below

typedef __bf16 bf16x8 __attribute__((ext_vector_type(8)));
typedef float  f32x4  __attribute__((ext_vector_type(4)));
typedef unsigned short u16x8 __attribute__((ext_vector_type(8)));

__device__ __forceinline__ unsigned short f2bf(float f) {
    unsigned u = __builtin_bit_cast(unsigned, f);
    u += 0x7fffu + ((u >> 16) & 1u);   // RNE
    return (unsigned short)(u >> 16);
}

// ---------- K0a: W_comb (fp64) [8][256] + b_comb (fp64) [8] ----------
__global__ __launch_bounds__(256) void k_comb(const float* __restrict__ Wb,
                                              const float* __restrict__ bb,
                                              const float* __restrict__ We,
                                              const float* __restrict__ be,
                                              double* __restrict__ Wcomb,
                                              double* __restrict__ bcomb) {
    int b = blockIdx.x, k = threadIdx.x;
    double acc = 0.0;
    for (int h = 0; h < 256; ++h)
        acc += (double)Wb[k * 256 + h] * (double)We[b * 256 + h];
    Wcomb[b * 256 + k] = acc;
    if (k == 0) {
        double a2 = (double)be[b];
        for (int h = 0; h < 256; ++h)
            a2 += (double)bb[h] * (double)We[b * 256 + h];
        bcomb[b] = a2;
    }
}

// ---------- K0b: W_fold bf16 [8][128 c][256 k] + b_fold f32 [8][128] ----------
__global__ __launch_bounds__(256) void k_fold(const float* __restrict__ Wb,
                                              const float* __restrict__ bb,
                                              const float* __restrict__ Wc,
                                              const float* __restrict__ bc,
                                              unsigned short* __restrict__ Wfold,
                                              float* __restrict__ bfold) {
    __shared__ float clf[32][128];   // [h][c]
    __shared__ float wbt[32][16];    // [h][k_local]
    int b = blockIdx.y, kg = blockIdx.x;   // kg: 16-k chunk
    int tid = threadIdx.x;
    int c = tid & 127, kh = tid >> 7;       // kh in {0,1}: k-octet

    float acc[8];
#pragma unroll
    for (int j = 0; j < 8; ++j) acc[j] = 0.f;

    for (int ht = 0; ht < 8; ++ht) {
#pragma unroll
        for (int j = 0; j < 16; ++j) {
            int idx = tid + j * 256;
            int hh = idx >> 7, cc = idx & 127;
            clf[hh][cc] = Wc[(b * 256 + ht * 32 + hh) * 128 + cc];
        }
#pragma unroll
        for (int j = 0; j < 2; ++j) {
            int idx = tid + j * 256;
            int hh = idx & 31, kk = idx >> 5;
            wbt[hh][kk] = Wb[(kg * 16 + kk) * 256 + ht * 32 + hh];
        }
        __syncthreads();
        for (int h = 0; h < 32; ++h) {
            float wc = clf[h][c];
            float4 w0 = *(const float4*)&wbt[h][kh * 8];
            float4 w1 = *(const float4*)&wbt[h][kh * 8 + 4];
            acc[0] += w0.x * wc; acc[1] += w0.y * wc;
            acc[2] += w0.z * wc; acc[3] += w0.w * wc;
            acc[4] += w1.x * wc; acc[5] += w1.y * wc;
            acc[6] += w1.z * wc; acc[7] += w1.w * wc;
        }
        __syncthreads();
    }
    // write 8 consecutive bf16 along k: Wfold[b][c][kg*16 + kh*8 + j]
    unsigned short o8[8];
#pragma unroll
    for (int j = 0; j < 8; ++j) o8[j] = f2bf(acc[j]);
    u16x8 pk;
#pragma unroll
    for (int j = 0; j < 8; ++j) pk[j] = o8[j];
    int base = (b * 128 + c) * 256 + kg * 16 + kh * 8;
    *(u16x8*)&Wfold[base] = pk;

    if (kg == 0 && tid < 128) {   // b_fold[b][c]
        float a = bc[b * 128 + tid];
        for (int h = 0; h < 256; ++h)
            a += bb[h] * Wc[(b * 256 + h) * 128 + tid];
        bfold[b * 128 + tid] = a;
    }
}

// ---------- main: fused route + grouped MFMA ----------
// Dynamic LDS layout (bytes):
//   xbf   : [128][264] ushort            0 .. 67584   (row pad 8 -> conflict-light, 16B aligned)
//   bid   : int[128]                 67584 .. 68096
//   cnt   : int[8]                   68096 .. 68128
//   ngv   : int[1]                   68128 .. 68132
//   grp_b : int[16]                  68132 .. 68196
//   grp_s : int[16]                  68196 .. 68260
//   list  : ushort[8][128]           68260 .. 70308
__global__ __launch_bounds__(256) void k_main(const float* __restrict__ x,
                                              const double* __restrict__ Wcomb,
                                              const double* __restrict__ bcomb,
                                              const unsigned short* __restrict__ Wfold,
                                              const float* __restrict__ bfold,
                                              float* __restrict__ out) {
    extern __shared__ unsigned char smem[];
    unsigned short* xbf = (unsigned short*)smem;
    int* bid   = (int*)(smem + 67584);
    int* cnt   = (int*)(smem + 68096);
    int* ngv   = (int*)(smem + 68128);
    int* grp_b = (int*)(smem + 68132);
    int* grp_s = (int*)(smem + 68196);
    unsigned short* list = (unsigned short*)(smem + 68260);

    int tid = threadIdx.x;
    int row0 = blockIdx.x * RROWS;

    // ---- phase 1a: x -> bf16 LDS (rows padded to 264 ushorts) ----
    const float4* xg = (const float4*)(x + (size_t)row0 * 256);
#pragma unroll 4
    for (int i = 0; i < 32; ++i) {
        float4 v = xg[i * 256 + tid];
        int e = (i * 256 + tid) * 4;
        int r = e >> 8, k = e & 255;
        ushort4 pk4;
        pk4.x = f2bf(v.x); pk4.y = f2bf(v.y); pk4.z = f2bf(v.z); pk4.w = f2bf(v.w);
        *(ushort4*)&xbf[r * 264 + k] = pk4;
    }

    // ---- phase 1b: fp64 est + per-row argmin (8-lane shuffle groups) ----
    {
        int b = tid & 7, rr = tid >> 3;               // lane-b, row group
        const double* wc = Wcomb + b * 256;
        for (int i = 0; i < 4; ++i) {
            int r = rr + 32 * i;
            const float* xr = x + (size_t)(row0 + r) * 256;
            double a0 = bcomb[b], a1 = 0.0, a2 = 0.0, a3 = 0.0;
            for (int k = 0; k < 256; k += 8) {
                float4 xv0 = *(const float4*)(xr + k);
                float4 xv1 = *(const float4*)(xr + k + 4);
                double2 w0 = *(const double2*)(wc + k);
                double2 w1 = *(const double2*)(wc + k + 2);
                double2 w2 = *(const double2*)(wc + k + 4);
                double2 w3 = *(const double2*)(wc + k + 6);
                a0 += (double)xv0.x * w0.x; a1 += (double)xv0.y * w0.y;
                a2 += (double)xv0.z * w1.x; a3 += (double)xv0.w * w1.y;
                a0 += (double)xv1.x * w2.x; a1 += (double)xv1.y * w2.y;
                a2 += (double)xv1.z * w3.x; a3 += (double)xv1.w * w3.y;
            }
            double best = (a0 + a2) + (a1 + a3);
            int bbx = b;
            for (int d = 4; d; d >>= 1) {
                double o  = __shfl_down(best, (unsigned)d, 8);
                int    ob = __shfl_down(bbx,  (unsigned)d, 8);
                if (o < best || (o == best && ob < bbx)) { best = o; bbx = ob; }
            }
            if (b == 0) bid[r] = bbx;
        }
    }
    if (tid < 8) cnt[tid] = 0;
    __syncthreads();

    // ---- phase 2: group rows by branch ----
    if (tid < 128) {
        int b2 = bid[tid];
        int p = atomicAdd(&cnt[b2], 1);
        list[b2 * 128 + p] = (unsigned short)tid;
    }
    __syncthreads();
    if (tid == 0) {
        int g = 0;
        for (int b2 = 0; b2 < 8; ++b2)
            for (int s = 0; s < cnt[b2]; s += 16) { grp_b[g] = b2; grp_s[g] = s; ++g; }
        ngv[0] = g;
    }
    __syncthreads();

    // ---- phase 3: 16x16x32 bf16 MFMA per (group, col-tile) ----
    int wave = tid >> 6, lane = tid & 63;
    int quad = lane >> 4, n16 = lane & 15;
    int G = ngv[0];

    for (int ctI = 0; ctI < 2; ++ctI) {
        int ct = wave + 4 * ctI;          // col tile 0..7 (16 cols each)
        int prev_b = -1;
        bf16x8 Bf[8];
        for (int g = 0; g < G; ++g) {
            int b3 = grp_b[g], s = grp_s[g];
            int mcnt = cnt[b3];
            if (b3 != prev_b) {
                const unsigned short* wp = Wfold + ((size_t)(b3 * 128 + ct * 16 + n16)) * 256 + quad * 8;
#pragma unroll
                for (int kt = 0; kt < 8; ++kt)
                    Bf[kt] = __builtin_bit_cast(bf16x8, *(const u16x8*)(wp + kt * 32));
                prev_b = b3;
            }
            int ri = s + n16; if (ri >= mcnt) ri = s;
            int ra = list[b3 * 128 + ri];
            const unsigned short* ap = &xbf[ra * 264 + quad * 8];
            bf16x8 Af[8];
#pragma unroll
            for (int kt = 0; kt < 8; ++kt)
                Af[kt] = __builtin_bit_cast(bf16x8, *(const u16x8*)(ap + kt * 32));

            float bias = bfold[b3 * 128 + ct * 16 + n16];
            f32x4 acc = {bias, bias, bias, bias};
#pragma unroll
            for (int kt = 0; kt < 8; ++kt)
                acc = __builtin_amdgcn_mfma_f32_16x16x32_bf16(Af[kt], Bf[kt], acc, 0, 0, 0);

#pragma unroll
            for (int reg = 0; reg < 4; ++reg) {
                int r16 = s + quad * 4 + reg;
                if (r16 < mcnt) {
                    int rw = list[b3 * 128 + r16];
                    out[(size_t)(row0 + rw) * 128 + ct * 16 + n16] = acc[reg];
                }
            }
        }
    }
}

extern "C" void kernel_launch(void* const* d_in, const int* in_sizes, int n_in,
                              void* d_out, int out_size, void* d_ws, size_t ws_size,
                              hipStream_t stream) {
    const float* x  = (const float*)d_in[0];
    const float* Wb = (const float*)d_in[1];
    const float* bb = (const float*)d_in[2];
    const float* Wc = (const float*)d_in[3];
    const float* bc = (const float*)d_in[4];
    const float* We = (const float*)d_in[5];
    const float* be = (const float*)d_in[6];
    float* out = (float*)d_out;

    unsigned char* ws = (unsigned char*)d_ws;
    double* Wcomb = (double*)ws;                               // 16384 B
    double* bcomb = (double*)(ws + 16384);                     // 64 B
    unsigned short* Wfold = (unsigned short*)(ws + 16448);     // 524288 B
    float* bfold = (float*)(ws + 540736);                      // 4096 B

    hipLaunchKernelGGL(k_comb, dim3(8), dim3(256), 0, stream, Wb, bb, We, be, Wcomb, bcomb);
    hipLaunchKernelGGL(k_fold, dim3(16, 8), dim3(256), 0, stream, Wb, bb, Wc, bc, Wfold, bfold);

    (void)hipFuncSetAttribute(reinterpret_cast<const void*>(k_main),
                              hipFuncAttributeMaxDynamicSharedMemorySize, SMEM_MAIN);
    hipLaunchKernelGGL(k_main, dim3(NROWS / RROWS), dim3(256), SMEM_MAIN, stream,
                       x, Wcomb, bcomb, Wfold, bfold, out);
}

// Round 2
// 542.676 us; speedup vs baseline: 1.0253x; 1.0253x over previous
//
#include <hip/hip_runtime.h>

// BranchNet: out[n] = x[n] @ W_fold[argmin_b(x[n]@W_comb[:,b]+b_comb[b])] + b_fold[sel]
// W_comb = W_base@W_est.T (fp64), W_fold[b] = W_base@W_clf[b] (bf16, [b][c][k]).
// Sizes: N=131072, IN=256, HID=256, B=8, C=128.

#define NROWS  131072
#define RROWS  128          // rows per block in main kernel
#define SMEM_MAIN 70308     // see layout below

typedef __bf16 bf16x8 __attribute__((ext_vector_type(8)));
typedef float  f32x4  __attribute__((ext_vector_type(4)));
typedef unsigned short u16x8 __attribute__((ext_vector_type(8)));

__device__ __forceinline__ unsigned short f2bf(float f) {
    unsigned u = __builtin_bit_cast(unsigned, f);
    u += 0x7fffu + ((u >> 16) & 1u);   // RNE
    return (unsigned short)(u >> 16);
}

// ---------- K0a: W_comb (fp64) [8][256] + b_comb (fp64) [8] ----------
__global__ __launch_bounds__(256) void k_comb(const float* __restrict__ Wb,
                                              const float* __restrict__ bb,
                                              const float* __restrict__ We,
                                              const float* __restrict__ be,
                                              double* __restrict__ Wcomb,
                                              double* __restrict__ bcomb) {
    __shared__ double red[256];
    int b = blockIdx.x, k = threadIdx.x;
    double a0 = 0.0, a1 = 0.0, a2 = 0.0, a3 = 0.0;
#pragma unroll 4
    for (int h = 0; h < 256; h += 4) {
        a0 += (double)Wb[k * 256 + h]     * (double)We[b * 256 + h];
        a1 += (double)Wb[k * 256 + h + 1] * (double)We[b * 256 + h + 1];
        a2 += (double)Wb[k * 256 + h + 2] * (double)We[b * 256 + h + 2];
        a3 += (double)Wb[k * 256 + h + 3] * (double)We[b * 256 + h + 3];
    }
    Wcomb[b * 256 + k] = (a0 + a1) + (a2 + a3);

    // b_comb: parallel tree reduction (was a single-thread 256-iter chain)
    red[k] = (double)bb[k] * (double)We[b * 256 + k];
    __syncthreads();
    for (int s = 128; s; s >>= 1) {
        if (k < s) red[k] += red[k + s];
        __syncthreads();
    }
    if (k == 0) bcomb[b] = red[0] + (double)be[b];
}

// ---------- K0b: W_fold bf16 [8][128 c][256 k] + b_fold f32 [8][128] ----------
__global__ __launch_bounds__(256) void k_fold(const float* __restrict__ Wb,
                                              const float* __restrict__ bb,
                                              const float* __restrict__ Wc,
                                              const float* __restrict__ bc,
                                              unsigned short* __restrict__ Wfold,
                                              float* __restrict__ bfold) {
    __shared__ float clf[32][128];   // [h][c]
    __shared__ float wbt[32][16];    // [h][k_local]
    int b = blockIdx.y, kg = blockIdx.x;   // kg: 16-k chunk
    int tid = threadIdx.x;
    int c = tid & 127, kh = tid >> 7;       // kh in {0,1}: k-octet

    float acc[8];
#pragma unroll
    for (int j = 0; j < 8; ++j) acc[j] = 0.f;

    for (int ht = 0; ht < 8; ++ht) {
#pragma unroll
        for (int j = 0; j < 16; ++j) {
            int idx = tid + j * 256;
            int hh = idx >> 7, cc = idx & 127;
            clf[hh][cc] = Wc[(b * 256 + ht * 32 + hh) * 128 + cc];
        }
#pragma unroll
        for (int j = 0; j < 2; ++j) {
            int idx = tid + j * 256;
            int hh = idx & 31, kk = idx >> 5;
            wbt[hh][kk] = Wb[(kg * 16 + kk) * 256 + ht * 32 + hh];
        }
        __syncthreads();
        for (int h = 0; h < 32; ++h) {
            float wc = clf[h][c];
            float4 w0 = *(const float4*)&wbt[h][kh * 8];
            float4 w1 = *(const float4*)&wbt[h][kh * 8 + 4];
            acc[0] += w0.x * wc; acc[1] += w0.y * wc;
            acc[2] += w0.z * wc; acc[3] += w0.w * wc;
            acc[4] += w1.x * wc; acc[5] += w1.y * wc;
            acc[6] += w1.z * wc; acc[7] += w1.w * wc;
        }
        __syncthreads();
    }
    // write 8 consecutive bf16 along k: Wfold[b][c][kg*16 + kh*8 + j]
    unsigned short o8[8];
#pragma unroll
    for (int j = 0; j < 8; ++j) o8[j] = f2bf(acc[j]);
    u16x8 pk;
#pragma unroll
    for (int j = 0; j < 8; ++j) pk[j] = o8[j];
    int base = (b * 128 + c) * 256 + kg * 16 + kh * 8;
    *(u16x8*)&Wfold[base] = pk;

    if (kg == 0) {   // b_fold[b][c] — parallel: 2 threads per c, halves combined in LDS
        int half = tid >> 7;           // h-range [half*128, half*128+128)
        float a = 0.f;
#pragma unroll 8
        for (int hh = 0; hh < 128; ++hh) {
            int h = half * 128 + hh;
            a += bb[h] * Wc[(b * 256 + h) * 128 + c];
        }
        clf[half][c] = a;              // clf free after final barrier of main loop
        __syncthreads();
        if (tid < 128) bfold[b * 128 + tid] = bc[b * 128 + tid] + clf[0][tid] + clf[1][tid];
    }
}

// ---------- main: fused route + grouped MFMA ----------
// Dynamic LDS layout (bytes):
//   xbf   : [128][264] ushort            0 .. 67584   (row pad 8 -> conflict-light, 16B aligned)
//   bid   : int[128]                 67584 .. 68096
//   cnt   : int[8]                   68096 .. 68128
//   ngv   : int[1]                   68128 .. 68132
//   grp_b : int[16]                  68132 .. 68196
//   grp_s : int[16]                  68196 .. 68260
//   list  : ushort[8][128]           68260 .. 70308
// __launch_bounds__(256, 2): LDS caps us at 2 blocks/CU anyway; give the
// register allocator the full 256-VGPR budget so Af[8]+Bf[8] (64 VGPRs of
// MFMA fragments) stay resident instead of spilling/rematerializing.
__global__ __launch_bounds__(256, 2) void k_main(const float* __restrict__ x,
                                              const double* __restrict__ Wcomb,
                                              const double* __restrict__ bcomb,
                                              const unsigned short* __restrict__ Wfold,
                                              const float* __restrict__ bfold,
                                              float* __restrict__ out) {
    extern __shared__ unsigned char smem[];
    unsigned short* xbf = (unsigned short*)smem;
    int* bid   = (int*)(smem + 67584);
    int* cnt   = (int*)(smem + 68096);
    int* ngv   = (int*)(smem + 68128);
    int* grp_b = (int*)(smem + 68132);
    int* grp_s = (int*)(smem + 68196);
    unsigned short* list = (unsigned short*)(smem + 68260);

    int tid = threadIdx.x;
    int row0 = blockIdx.x * RROWS;

    // ---- phase 1a: x -> bf16 LDS (rows padded to 264 ushorts) ----
    const float4* xg = (const float4*)(x + (size_t)row0 * 256);
#pragma unroll 4
    for (int i = 0; i < 32; ++i) {
        float4 v = xg[i * 256 + tid];
        int e = (i * 256 + tid) * 4;
        int r = e >> 8, k = e & 255;
        ushort4 pk4;
        pk4.x = f2bf(v.x); pk4.y = f2bf(v.y); pk4.z = f2bf(v.z); pk4.w = f2bf(v.w);
        *(ushort4*)&xbf[r * 264 + k] = pk4;
    }

    // ---- phase 1b: fp64 est + per-row argmin (8-lane shuffle groups) ----
    {
        int b = tid & 7, rr = tid >> 3;               // lane-b, row group
        const double* wc = Wcomb + b * 256;
        for (int i = 0; i < 4; ++i) {
            int r = rr + 32 * i;
            const float* xr = x + (size_t)(row0 + r) * 256;
            double a0 = bcomb[b], a1 = 0.0, a2 = 0.0, a3 = 0.0;
            for (int k = 0; k < 256; k += 8) {
                float4 xv0 = *(const float4*)(xr + k);
                float4 xv1 = *(const float4*)(xr + k + 4);
                double2 w0 = *(const double2*)(wc + k);
                double2 w1 = *(const double2*)(wc + k + 2);
                double2 w2 = *(const double2*)(wc + k + 4);
                double2 w3 = *(const double2*)(wc + k + 6);
                a0 += (double)xv0.x * w0.x; a1 += (double)xv0.y * w0.y;
                a2 += (double)xv0.z * w1.x; a3 += (double)xv0.w * w1.y;
                a0 += (double)xv1.x * w2.x; a1 += (double)xv1.y * w2.y;
                a2 += (double)xv1.z * w3.x; a3 += (double)xv1.w * w3.y;
            }
            double best = (a0 + a2) + (a1 + a3);
            int bbx = b;
            for (int d = 4; d; d >>= 1) {
                double o  = __shfl_down(best, (unsigned)d, 8);
                int    ob = __shfl_down(bbx,  (unsigned)d, 8);
                if (o < best || (o == best && ob < bbx)) { best = o; bbx = ob; }
            }
            if (b == 0) bid[r] = bbx;
        }
    }
    if (tid < 8) cnt[tid] = 0;
    __syncthreads();

    // ---- phase 2: group rows by branch ----
    if (tid < 128) {
        int b2 = bid[tid];
        int p = atomicAdd(&cnt[b2], 1);
        list[b2 * 128 + p] = (unsigned short)tid;
    }
    __syncthreads();
    if (tid == 0) {
        int g = 0;
        for (int b2 = 0; b2 < 8; ++b2)
            for (int s = 0; s < cnt[b2]; s += 16) { grp_b[g] = b2; grp_s[g] = s; ++g; }
        ngv[0] = g;
    }
    __syncthreads();

    // ---- phase 3: 16x16x32 bf16 MFMA per (group, col-tile) ----
    int wave = tid >> 6, lane = tid & 63;
    int quad = lane >> 4, n16 = lane & 15;
    int G = ngv[0];

    for (int ctI = 0; ctI < 2; ++ctI) {
        int ct = wave + 4 * ctI;          // col tile 0..7 (16 cols each)
        int prev_b = -1;
        bf16x8 Bf[8];
        for (int g = 0; g < G; ++g) {
            int b3 = grp_b[g], s = grp_s[g];
            int mcnt = cnt[b3];
            if (b3 != prev_b) {
                const unsigned short* wp = Wfold + ((size_t)(b3 * 128 + ct * 16 + n16)) * 256 + quad * 8;
#pragma unroll
                for (int kt = 0; kt < 8; ++kt)
                    Bf[kt] = __builtin_bit_cast(bf16x8, *(const u16x8*)(wp + kt * 32));
                prev_b = b3;
            }
            int ri = s + n16; if (ri >= mcnt) ri = s;
            int ra = list[b3 * 128 + ri];
            const unsigned short* ap = &xbf[ra * 264 + quad * 8];
            bf16x8 Af[8];
#pragma unroll
            for (int kt = 0; kt < 8; ++kt)
                Af[kt] = __builtin_bit_cast(bf16x8, *(const u16x8*)(ap + kt * 32));

            float bias = bfold[b3 * 128 + ct * 16 + n16];
            f32x4 acc = {bias, bias, bias, bias};
#pragma unroll
            for (int kt = 0; kt < 8; ++kt)
                acc = __builtin_amdgcn_mfma_f32_16x16x32_bf16(Af[kt], Bf[kt], acc, 0, 0, 0);

#pragma unroll
            for (int reg = 0; reg < 4; ++reg) {
                int r16 = s + quad * 4 + reg;
                if (r16 < mcnt) {
                    int rw = list[b3 * 128 + r16];
                    out[(size_t)(row0 + rw) * 128 + ct * 16 + n16] = acc[reg];
                }
            }
        }
    }
}

extern "C" void kernel_launch(void* const* d_in, const int* in_sizes, int n_in,
                              void* d_out, int out_size, void* d_ws, size_t ws_size,
                              hipStream_t stream) {
    const float* x  = (const float*)d_in[0];
    const float* Wb = (const float*)d_in[1];
    const float* bb = (const float*)d_in[2];
    const float* Wc = (const float*)d_in[3];
    const float* bc = (const float*)d_in[4];
    const float* We = (const float*)d_in[5];
    const float* be = (const float*)d_in[6];
    float* out = (float*)d_out;

    unsigned char* ws = (unsigned char*)d_ws;
    double* Wcomb = (double*)ws;                               // 16384 B
    double* bcomb = (double*)(ws + 16384);                     // 64 B
    unsigned short* Wfold = (unsigned short*)(ws + 16448);     // 524288 B
    float* bfold = (float*)(ws + 540736);                      // 4096 B

    hipLaunchKernelGGL(k_comb, dim3(8), dim3(256), 0, stream, Wb, bb, We, be, Wcomb, bcomb);
    hipLaunchKernelGGL(k_fold, dim3(16, 8), dim3(256), 0, stream, Wb, bb, Wc, bc, Wfold, bfold);

    (void)hipFuncSetAttribute(reinterpret_cast<const void*>(k_main),
                              hipFuncAttributeMaxDynamicSharedMemorySize, SMEM_MAIN);
    hipLaunchKernelGGL(k_main, dim3(NROWS / RROWS), dim3(256), SMEM_MAIN, stream,
                       x, Wcomb, bcomb, Wfold, bfold, out);
}

// Round 3
// 526.396 us; speedup vs baseline: 1.0570x; 1.0309x over previous
//
#include <hip/hip_runtime.h>

// BranchNet: out[n] = x[n] @ W_fold[argmin_b(x[n]@W_comb[:,b]+b_comb[b])] + b_fold[sel]
// W_comb = W_base@W_est.T (fp64), W_fold[b] = W_base@W_clf[b] (bf16, [b][c][k]).
// Sizes: N=131072, IN=256, HID=256, B=8, C=128.

#define NROWS  131072
#define RROWS  128          // rows per block in main kernel
#define TPB    1024         // 16 waves/block; 2 blocks/CU (LDS) -> 32 waves/CU (max TLP)
#define SMEM_MAIN 70308

typedef __bf16 bf16x8 __attribute__((ext_vector_type(8)));
typedef float  f32x4  __attribute__((ext_vector_type(4)));
typedef unsigned short u16x8 __attribute__((ext_vector_type(8)));

__device__ __forceinline__ unsigned short f2bf(float f) {
    unsigned u = __builtin_bit_cast(unsigned, f);
    u += 0x7fffu + ((u >> 16) & 1u);   // RNE
    return (unsigned short)(u >> 16);
}

// ---------- merged prep: blocks 0..7 = comb(b), blocks 8..135 = fold(kg,b) ----------
__global__ __launch_bounds__(256) void k_prep(const float* __restrict__ Wb,
                                              const float* __restrict__ bb,
                                              const float* __restrict__ Wc,
                                              const float* __restrict__ bc,
                                              const float* __restrict__ We,
                                              const float* __restrict__ be,
                                              double* __restrict__ Wcomb,
                                              double* __restrict__ bcomb,
                                              unsigned short* __restrict__ Wfold,
                                              float* __restrict__ bfold) {
    __shared__ float clf[32][128];   // fold: [h][c]
    __shared__ float wbt[32][16];    // fold: [h][k_local]
    __shared__ double red[256];      // comb: reduction
    int blk = blockIdx.x, tid = threadIdx.x;

    if (blk < 8) {
        // ---- comb: W_comb[b][k] fp64, float4 loads, 4-acc grouping matches h%4 ----
        int b = blk, k = tid;
        const float4* wbr = (const float4*)(Wb + k * 256);
        const float4* wer = (const float4*)(We + b * 256);
        double a0 = 0.0, a1 = 0.0, a2 = 0.0, a3 = 0.0;
#pragma unroll 8
        for (int j = 0; j < 64; ++j) {
            float4 u = wbr[j], w = wer[j];
            a0 += (double)u.x * (double)w.x;
            a1 += (double)u.y * (double)w.y;
            a2 += (double)u.z * (double)w.z;
            a3 += (double)u.w * (double)w.w;
        }
        Wcomb[b * 256 + k] = (a0 + a1) + (a2 + a3);

        red[k] = (double)bb[k] * (double)We[b * 256 + k];
        __syncthreads();
        for (int s = 128; s; s >>= 1) {
            if (k < s) red[k] += red[k + s];
            __syncthreads();
        }
        if (k == 0) bcomb[b] = red[0] + (double)be[b];
        return;
    }

    // ---- fold: Wfold[b][c][k] bf16 ----
    int idx0 = blk - 8;
    int kg = idx0 & 15, b = idx0 >> 4;
    int c = tid & 127, kh = tid >> 7;

    float acc[8];
#pragma unroll
    for (int j = 0; j < 8; ++j) acc[j] = 0.f;

    for (int ht = 0; ht < 8; ++ht) {
#pragma unroll
        for (int j = 0; j < 16; ++j) {
            int idx = tid + j * 256;
            int hh = idx >> 7, cc = idx & 127;
            clf[hh][cc] = Wc[(b * 256 + ht * 32 + hh) * 128 + cc];
        }
#pragma unroll
        for (int j = 0; j < 2; ++j) {
            int idx = tid + j * 256;
            int hh = idx & 31, kk = idx >> 5;
            wbt[hh][kk] = Wb[(kg * 16 + kk) * 256 + ht * 32 + hh];
        }
        __syncthreads();
        for (int h = 0; h < 32; ++h) {
            float wc = clf[h][c];
            float4 w0 = *(const float4*)&wbt[h][kh * 8];
            float4 w1 = *(const float4*)&wbt[h][kh * 8 + 4];
            acc[0] += w0.x * wc; acc[1] += w0.y * wc;
            acc[2] += w0.z * wc; acc[3] += w0.w * wc;
            acc[4] += w1.x * wc; acc[5] += w1.y * wc;
            acc[6] += w1.z * wc; acc[7] += w1.w * wc;
        }
        __syncthreads();
    }
    unsigned short o8[8];
#pragma unroll
    for (int j = 0; j < 8; ++j) o8[j] = f2bf(acc[j]);
    u16x8 pk;
#pragma unroll
    for (int j = 0; j < 8; ++j) pk[j] = o8[j];
    int base = (b * 128 + c) * 256 + kg * 16 + kh * 8;
    *(u16x8*)&Wfold[base] = pk;

    if (kg == 0) {   // b_fold[b][c]: 2 threads per c
        int half = tid >> 7;
        float a = 0.f;
#pragma unroll 8
        for (int hh = 0; hh < 128; ++hh) {
            int h = half * 128 + hh;
            a += bb[h] * Wc[(b * 256 + h) * 128 + c];
        }
        clf[half][c] = a;
        __syncthreads();
        if (tid < 128) bfold[b * 128 + tid] = bc[b * 128 + tid] + clf[0][tid] + clf[1][tid];
    }
}

// ---------- main: fused route + grouped MFMA, 1024 threads ----------
// Dynamic LDS layout (bytes):
//   xbf   : [128][264] ushort            0 .. 67584
//   bid   : int[128]                 67584 .. 68096
//   cnt   : int[8]                   68096 .. 68128
//   ngv   : int[1]                   68128 .. 68132
//   grp_b : int[16]                  68132 .. 68196
//   grp_s : int[16]                  68196 .. 68260
//   list  : ushort[8][128]           68260 .. 70308
__global__ __launch_bounds__(TPB) void k_main(const float* __restrict__ x,
                                              const double* __restrict__ Wcomb,
                                              const double* __restrict__ bcomb,
                                              const unsigned short* __restrict__ Wfold,
                                              const float* __restrict__ bfold,
                                              float* __restrict__ out) {
    extern __shared__ unsigned char smem[];
    unsigned short* xbf = (unsigned short*)smem;
    int* bid   = (int*)(smem + 67584);
    int* cnt   = (int*)(smem + 68096);
    int* ngv   = (int*)(smem + 68128);
    int* grp_b = (int*)(smem + 68132);
    int* grp_s = (int*)(smem + 68196);
    unsigned short* list = (unsigned short*)(smem + 68260);

    int tid = threadIdx.x;
    int row0 = blockIdx.x * RROWS;

    // ---- phase 1a: x -> bf16 LDS (8 independent 16B loads/thread) ----
    const float4* xg = (const float4*)(x + (size_t)row0 * 256);
#pragma unroll
    for (int i = 0; i < 8; ++i) {
        float4 v = xg[i * 1024 + tid];
        int e = i * 1024 + tid;          // float4 index
        int r = e >> 6, k = (e & 63) * 4;
        ushort4 pk4;
        pk4.x = f2bf(v.x); pk4.y = f2bf(v.y); pk4.z = f2bf(v.z); pk4.w = f2bf(v.w);
        *(ushort4*)&xbf[r * 264 + k] = pk4;
    }

    // ---- phase 1b: fp64 est + argmin; one row per 8-lane octet ----
    {
        int b = tid & 7, r = tid >> 3;    // r in [0,128)
        const double* wc = Wcomb + b * 256;
        const float* xr = x + (size_t)(row0 + r) * 256;
        double a0 = bcomb[b], a1 = 0.0, a2 = 0.0, a3 = 0.0;
        for (int k = 0; k < 256; k += 8) {
            float4 xv0 = *(const float4*)(xr + k);
            float4 xv1 = *(const float4*)(xr + k + 4);
            double2 w0 = *(const double2*)(wc + k);
            double2 w1 = *(const double2*)(wc + k + 2);
            double2 w2 = *(const double2*)(wc + k + 4);
            double2 w3 = *(const double2*)(wc + k + 6);
            a0 += (double)xv0.x * w0.x; a1 += (double)xv0.y * w0.y;
            a2 += (double)xv0.z * w1.x; a3 += (double)xv0.w * w1.y;
            a0 += (double)xv1.x * w2.x; a1 += (double)xv1.y * w2.y;
            a2 += (double)xv1.z * w3.x; a3 += (double)xv1.w * w3.y;
        }
        double best = (a0 + a2) + (a1 + a3);
        int bbx = b;
        for (int d = 4; d; d >>= 1) {
            double o  = __shfl_down(best, (unsigned)d, 8);
            int    ob = __shfl_down(bbx,  (unsigned)d, 8);
            if (o < best || (o == best && ob < bbx)) { best = o; bbx = ob; }
        }
        if (b == 0) bid[r] = bbx;
    }
    if (tid < 8) cnt[tid] = 0;
    __syncthreads();

    // ---- phase 2: group rows by branch ----
    if (tid < 128) {
        int b2 = bid[tid];
        int p = atomicAdd(&cnt[b2], 1);
        list[b2 * 128 + p] = (unsigned short)tid;
    }
    __syncthreads();
    if (tid == 0) {
        int g = 0;
        for (int b2 = 0; b2 < 8; ++b2)
            for (int s = 0; s < cnt[b2]; s += 16) { grp_b[g] = b2; grp_s[g] = s; ++g; }
        ngv[0] = g;
    }
    __syncthreads();

    // ---- phase 3: 16 waves; wave = (half, ct); contiguous group halves ----
    int wave = tid >> 6, lane = tid & 63;
    int quad = lane >> 4, n16 = lane & 15;
    int ct = wave & 7, half = wave >> 3;
    int G = ngv[0];
    int gmid = (G + 1) >> 1;
    int g0 = half ? gmid : 0;
    int g1 = half ? G : gmid;

    int prev_b = -1;
    bf16x8 Bf[8];
    for (int g = g0; g < g1; ++g) {
        int b3 = grp_b[g], s = grp_s[g];
        int mcnt = cnt[b3];
        if (b3 != prev_b) {
            const unsigned short* wp = Wfold + ((size_t)(b3 * 128 + ct * 16 + n16)) * 256 + quad * 8;
#pragma unroll
            for (int kt = 0; kt < 8; ++kt)
                Bf[kt] = __builtin_bit_cast(bf16x8, *(const u16x8*)(wp + kt * 32));
            prev_b = b3;
        }
        int ri = s + n16; if (ri >= mcnt) ri = s;
        int ra = list[b3 * 128 + ri];
        const unsigned short* ap = &xbf[ra * 264 + quad * 8];
        bf16x8 Af[8];
#pragma unroll
        for (int kt = 0; kt < 8; ++kt)
            Af[kt] = __builtin_bit_cast(bf16x8, *(const u16x8*)(ap + kt * 32));

        float bias = bfold[b3 * 128 + ct * 16 + n16];
        f32x4 acc = {bias, bias, bias, bias};
#pragma unroll
        for (int kt = 0; kt < 8; ++kt)
            acc = __builtin_amdgcn_mfma_f32_16x16x32_bf16(Af[kt], Bf[kt], acc, 0, 0, 0);

#pragma unroll
        for (int reg = 0; reg < 4; ++reg) {
            int r16 = s + quad * 4 + reg;
            if (r16 < mcnt) {
                int rw = list[b3 * 128 + r16];
                out[(size_t)(row0 + rw) * 128 + ct * 16 + n16] = acc[reg];
            }
        }
    }
}

extern "C" void kernel_launch(void* const* d_in, const int* in_sizes, int n_in,
                              void* d_out, int out_size, void* d_ws, size_t ws_size,
                              hipStream_t stream) {
    const float* x  = (const float*)d_in[0];
    const float* Wb = (const float*)d_in[1];
    const float* bb = (const float*)d_in[2];
    const float* Wc = (const float*)d_in[3];
    const float* bc = (const float*)d_in[4];
    const float* We = (const float*)d_in[5];
    const float* be = (const float*)d_in[6];
    float* out = (float*)d_out;

    unsigned char* ws = (unsigned char*)d_ws;
    double* Wcomb = (double*)ws;                               // 16384 B
    double* bcomb = (double*)(ws + 16384);                     // 64 B
    unsigned short* Wfold = (unsigned short*)(ws + 16448);     // 524288 B
    float* bfold = (float*)(ws + 540736);                      // 4096 B

    hipLaunchKernelGGL(k_prep, dim3(136), dim3(256), 0, stream,
                       Wb, bb, Wc, bc, We, be, Wcomb, bcomb, Wfold, bfold);

    (void)hipFuncSetAttribute(reinterpret_cast<const void*>(k_main),
                              hipFuncAttributeMaxDynamicSharedMemorySize, SMEM_MAIN);
    hipLaunchKernelGGL(k_main, dim3(NROWS / RROWS), dim3(TPB), SMEM_MAIN, stream,
                       x, Wcomb, bcomb, Wfold, bfold, out);
}

// Round 4
// 300.903 us; speedup vs baseline: 1.8492x; 1.7494x over previous
//
#include <hip/hip_runtime.h>

// BranchNet pipeline: k_prep (fold weights) -> k_route1 (fp64 routing + hist)
//   -> k_route2 (bucket compaction) -> k_gemm (per-branch dense MFMA tiles).
// W_comb = W_base@W_est.T (fp64), W_fold[b] = W_base@W_clf[b] (bf16, [b][c][k]).
// Sizes: N=131072, IN=256, HID=256, B=8, C=128.

#define NROWS 131072

typedef __bf16 bf16x8 __attribute__((ext_vector_type(8)));
typedef float  f32x4  __attribute__((ext_vector_type(4)));
typedef unsigned short u16x8 __attribute__((ext_vector_type(8)));

__device__ __forceinline__ unsigned short f2bf(float f) {
    unsigned u = __builtin_bit_cast(unsigned, f);
    u += 0x7fffu + ((u >> 16) & 1u);   // RNE
    return (unsigned short)(u >> 16);
}

// ---------- prep: blocks 0..7 comb(b) [+zero counters], 8..11 bfold, 12..139 fold ----------
__global__ __launch_bounds__(256) void k_prep(const float* __restrict__ Wb,
                                              const float* __restrict__ bb,
                                              const float* __restrict__ Wc,
                                              const float* __restrict__ bc,
                                              const float* __restrict__ We,
                                              const float* __restrict__ be,
                                              double* __restrict__ Wcomb,
                                              double* __restrict__ bcomb,
                                              unsigned short* __restrict__ Wfold,
                                              float* __restrict__ bfold,
                                              int* __restrict__ gzero) {
    __shared__ float clf[32][128];
    __shared__ float wbt[32][16];
    __shared__ double red[256];
    int blk = blockIdx.x, tid = threadIdx.x;

    if (blk < 8) {
        if (blk == 0 && tid < 16) gzero[tid] = 0;   // gcnt[8] + gofs[8]
        int b = blk, k = tid;
        const float4* wbr = (const float4*)(Wb + k * 256);
        const float4* wer = (const float4*)(We + b * 256);
        double a0 = 0.0, a1 = 0.0, a2 = 0.0, a3 = 0.0;
#pragma unroll 8
        for (int j = 0; j < 64; ++j) {
            float4 u = wbr[j], w = wer[j];
            a0 += (double)u.x * (double)w.x;
            a1 += (double)u.y * (double)w.y;
            a2 += (double)u.z * (double)w.z;
            a3 += (double)u.w * (double)w.w;
        }
        Wcomb[b * 256 + k] = (a0 + a1) + (a2 + a3);

        red[k] = (double)bb[k] * (double)We[b * 256 + k];
        __syncthreads();
        for (int s = 128; s; s >>= 1) {
            if (k < s) red[k] += red[k + s];
            __syncthreads();
        }
        if (k == 0) bcomb[b] = red[0] + (double)be[b];
        return;
    }

    if (blk < 12) {
        // b_fold[b][c] = bc[b][c] + sum_h bb[h]*Wc[b][h][c]; 2 branches per block
        int b = (blk - 8) * 2 + (tid >> 7);
        int c = tid & 127;
        float a = bc[b * 128 + c];
        for (int h = 0; h < 256; ++h)
            a += bb[h] * Wc[(b * 256 + h) * 128 + c];
        bfold[b * 128 + c] = a;
        return;
    }

    // fold: Wfold[b][c][k] bf16
    int idx0 = blk - 12;
    int kg = idx0 & 15, b = idx0 >> 4;
    int c = tid & 127, kh = tid >> 7;

    float acc[8];
#pragma unroll
    for (int j = 0; j < 8; ++j) acc[j] = 0.f;

    for (int ht = 0; ht < 8; ++ht) {
#pragma unroll
        for (int j = 0; j < 16; ++j) {
            int idx = tid + j * 256;
            int hh = idx >> 7, cc = idx & 127;
            clf[hh][cc] = Wc[(b * 256 + ht * 32 + hh) * 128 + cc];
        }
#pragma unroll
        for (int j = 0; j < 2; ++j) {
            int idx = tid + j * 256;
            int hh = idx & 31, kk = idx >> 5;
            wbt[hh][kk] = Wb[(kg * 16 + kk) * 256 + ht * 32 + hh];
        }
        __syncthreads();
        for (int h = 0; h < 32; ++h) {
            float wc = clf[h][c];
            float4 w0 = *(const float4*)&wbt[h][kh * 8];
            float4 w1 = *(const float4*)&wbt[h][kh * 8 + 4];
            acc[0] += w0.x * wc; acc[1] += w0.y * wc;
            acc[2] += w0.z * wc; acc[3] += w0.w * wc;
            acc[4] += w1.x * wc; acc[5] += w1.y * wc;
            acc[6] += w1.z * wc; acc[7] += w1.w * wc;
        }
        __syncthreads();
    }
    unsigned short o8[8];
#pragma unroll
    for (int j = 0; j < 8; ++j) o8[j] = f2bf(acc[j]);
    u16x8 pk;
#pragma unroll
    for (int j = 0; j < 8; ++j) pk[j] = o8[j];
    int base = (b * 128 + c) * 256 + kg * 16 + kh * 8;
    *(u16x8*)&Wfold[base] = pk;
}

// ---------- route1: fp64 est + argmin; 32 rows/block; bid + global hist ----------
// Accumulation order matches R3 exactly -> bitwise-identical est -> same argmin.
__global__ __launch_bounds__(256) void k_route1(const float* __restrict__ x,
                                                const double* __restrict__ Wcomb,
                                                const double* __restrict__ bcomb,
                                                unsigned char* __restrict__ bidg,
                                                int* __restrict__ gcnt) {
    __shared__ double wc[8 * 258];   // row stride 258 doubles -> banks 4b..4b+3, conflict-free
    __shared__ double bco[8];
    __shared__ int cnt[8];
    __shared__ unsigned char bidl[32];
    int tid = threadIdx.x;

    for (int j = tid; j < 2048; j += 256) {
        int b = j >> 8, k = j & 255;
        wc[b * 258 + k] = Wcomb[j];
    }
    if (tid < 8) { bco[tid] = bcomb[tid]; cnt[tid] = 0; }
    __syncthreads();

    int b = tid & 7, oct = tid >> 3;             // one row per 8-lane octet
    int row = blockIdx.x * 32 + oct;
    const float* xr = x + (size_t)row * 256;
    const double* wcr = wc + b * 258;
    double a0 = bco[b], a1 = 0.0, a2 = 0.0, a3 = 0.0;
    for (int k = 0; k < 256; k += 8) {
        float4 xv0 = *(const float4*)(xr + k);
        float4 xv1 = *(const float4*)(xr + k + 4);
        double2 w0 = *(const double2*)(wcr + k);
        double2 w1 = *(const double2*)(wcr + k + 2);
        double2 w2 = *(const double2*)(wcr + k + 4);
        double2 w3 = *(const double2*)(wcr + k + 6);
        a0 += (double)xv0.x * w0.x; a1 += (double)xv0.y * w0.y;
        a2 += (double)xv0.z * w1.x; a3 += (double)xv0.w * w1.y;
        a0 += (double)xv1.x * w2.x; a1 += (double)xv1.y * w2.y;
        a2 += (double)xv1.z * w3.x; a3 += (double)xv1.w * w3.y;
    }
    double best = (a0 + a2) + (a1 + a3);
    int bbx = b;
    for (int d = 4; d; d >>= 1) {
        double o  = __shfl_down(best, (unsigned)d, 8);
        int    ob = __shfl_down(bbx,  (unsigned)d, 8);
        if (o < best || (o == best && ob < bbx)) { best = o; bbx = ob; }
    }
    if (b == 0) { bidl[oct] = (unsigned char)bbx; atomicAdd(&cnt[bbx], 1); }
    __syncthreads();
    if (tid < 32) bidg[blockIdx.x * 32 + tid] = bidl[tid];
    if (tid < 8 && cnt[tid]) atomicAdd(&gcnt[tid], cnt[tid]);
}

// ---------- route2: compact rows into per-branch contiguous lists ----------
__global__ __launch_bounds__(256) void k_route2(const unsigned char* __restrict__ bidg,
                                                const int* __restrict__ gcnt,
                                                int* __restrict__ gofs,
                                                int* __restrict__ perm) {
    __shared__ int cnt[8], base8[8], gb[8];
    __shared__ unsigned short list[8][256];
    int tid = threadIdx.x;
    if (tid < 8) cnt[tid] = 0;
    __syncthreads();
    int row = blockIdx.x * 256 + tid;
    int b = bidg[row];
    int p = atomicAdd(&cnt[b], 1);
    list[b][p] = (unsigned short)tid;
    __syncthreads();
    if (tid == 0) {
        int s = 0;
        for (int i = 0; i < 8; ++i) { gb[i] = s; s += gcnt[i]; }
    }
    if (tid < 8) base8[tid] = cnt[tid] ? atomicAdd(&gofs[tid], cnt[tid]) : 0;
    __syncthreads();
    for (int j = tid; j < 2048; j += 256) {
        int bb2 = j >> 8, i = j & 255;
        if (i < cnt[bb2])
            perm[gb[bb2] + base8[bb2] + i] = blockIdx.x * 256 + (int)list[bb2][i];
    }
}

// ---------- gemm: one (branch, 64-row tile) x 128 cols per block ----------
__global__ __launch_bounds__(256) void k_gemm(const float* __restrict__ x,
                                              const int* __restrict__ gcnt,
                                              const int* __restrict__ perm,
                                              const unsigned short* __restrict__ Wfold,
                                              const float* __restrict__ bfold,
                                              float* __restrict__ out) {
    __shared__ unsigned short xbf[64 * 264];   // 33792 ushorts = 66 KB? no: 67584 B/2 -> 33.8 KB
    __shared__ int rowid[64];
    int tid = threadIdx.x;

    // block -> (branch b, tile) assignment from gcnt
    int t = blockIdx.x;
    int b = -1, tile = 0, pb = 0, m = 0;
    int accT = 0, accR = 0;
#pragma unroll
    for (int i = 0; i < 8; ++i) {
        int ci = gcnt[i];
        int Ti = (ci + 63) >> 6;
        if (b < 0 && t < accT + Ti) {
            b = i; tile = t - accT; pb = accR;
            int rem = ci - tile * 64;
            m = rem < 64 ? rem : 64;
        }
        accT += Ti; accR += ci;
    }
    if (b < 0) return;

    int pbase = pb + tile * 64;
    if (tid < 64) rowid[tid] = perm[pbase + (tid < m ? tid : 0)];
    __syncthreads();

    // stage 64 gathered rows -> bf16 LDS; one full row per wave-instruction
#pragma unroll 4
    for (int it = 0; it < 16; ++it) {
        int idx = it * 256 + tid;
        int r = idx >> 6, kq = idx & 63;
        float4 v = *(const float4*)(x + (size_t)rowid[r] * 256 + kq * 4);
        ushort4 pk4;
        pk4.x = f2bf(v.x); pk4.y = f2bf(v.y); pk4.z = f2bf(v.z); pk4.w = f2bf(v.w);
        *(ushort4*)&xbf[r * 264 + kq * 4] = pk4;
    }
    __syncthreads();

    int wave = tid >> 6, lane = tid & 63;
    int quad = lane >> 4, n16 = lane & 15;

    for (int cc = 0; cc < 2; ++cc) {
        int ct = wave + cc * 4;     // col tile 0..7
        const unsigned short* wp = Wfold + ((size_t)(b * 128 + ct * 16 + n16)) * 256 + quad * 8;
        bf16x8 Bf[8];
#pragma unroll
        for (int kt = 0; kt < 8; ++kt)
            Bf[kt] = __builtin_bit_cast(bf16x8, *(const u16x8*)(wp + kt * 32));
        float bias = bfold[b * 128 + ct * 16 + n16];

        for (int rg = 0; rg < 4; ++rg) {
            int s = rg * 16;
            const unsigned short* ap = &xbf[(s + n16) * 264 + quad * 8];
            bf16x8 Af[8];
#pragma unroll
            for (int kt = 0; kt < 8; ++kt)
                Af[kt] = __builtin_bit_cast(bf16x8, *(const u16x8*)(ap + kt * 32));

            f32x4 acc = {bias, bias, bias, bias};
#pragma unroll
            for (int kt = 0; kt < 8; ++kt)
                acc = __builtin_amdgcn_mfma_f32_16x16x32_bf16(Af[kt], Bf[kt], acc, 0, 0, 0);

#pragma unroll
            for (int reg = 0; reg < 4; ++reg) {
                int r16 = s + quad * 4 + reg;
                if (r16 < m)
                    out[(size_t)rowid[r16] * 128 + ct * 16 + n16] = acc[reg];
            }
        }
    }
}

extern "C" void kernel_launch(void* const* d_in, const int* in_sizes, int n_in,
                              void* d_out, int out_size, void* d_ws, size_t ws_size,
                              hipStream_t stream) {
    const float* x  = (const float*)d_in[0];
    const float* Wb = (const float*)d_in[1];
    const float* bb = (const float*)d_in[2];
    const float* Wc = (const float*)d_in[3];
    const float* bc = (const float*)d_in[4];
    const float* We = (const float*)d_in[5];
    const float* be = (const float*)d_in[6];
    float* out = (float*)d_out;

    unsigned char* ws = (unsigned char*)d_ws;
    double* Wcomb = (double*)ws;                               //       0 : 16384 B
    double* bcomb = (double*)(ws + 16384);                     //   16384 : 64 B
    unsigned short* Wfold = (unsigned short*)(ws + 16448);     //   16448 : 524288 B
    float* bfold = (float*)(ws + 540736);                      //  540736 : 4096 B
    int* gcnt = (int*)(ws + 544832);                           //  544832 : 32 B
    int* gofs = (int*)(ws + 544864);                           //  544864 : 32 B
    unsigned char* bidg = (unsigned char*)(ws + 544896);       //  544896 : 131072 B
    int* perm = (int*)(ws + 675968);                           //  675968 : 524288 B -> 1200256 total

    hipLaunchKernelGGL(k_prep, dim3(140), dim3(256), 0, stream,
                       Wb, bb, Wc, bc, We, be, Wcomb, bcomb, Wfold, bfold, gcnt);
    hipLaunchKernelGGL(k_route1, dim3(NROWS / 32), dim3(256), 0, stream,
                       x, Wcomb, bcomb, bidg, gcnt);
    hipLaunchKernelGGL(k_route2, dim3(NROWS / 256), dim3(256), 0, stream,
                       bidg, gcnt, gofs, perm);
    hipLaunchKernelGGL(k_gemm, dim3(NROWS / 64 + 7), dim3(256), 0, stream,
                       x, gcnt, perm, Wfold, bfold, out);
}